// Round 12
// baseline (696.302 us; speedup 1.0000x reference)
//
#include <hip/hip_runtime.h>
#include <hip/hip_bf16.h>

#define EMB 64
#define XCOLS 20
#define NSYMP 15
#define BSH 7
#define BSZ 128          // nodes per bucket (1<<BSH)
#define MAXNB 1024       // supports N <= 131072
#define PCHUNK 4096

__global__ void zero_kernel(int* __restrict__ p, int n) {
    int i = blockIdx.x * blockDim.x + threadIdx.x;
    if (i < n) p[i] = 0;
}

// ---------------- embedding ----------------
__global__ void embed_kernel(const int* __restrict__ x,
                             const float* __restrict__ bt,
                             const float* __restrict__ gt,
                             const float* __restrict__ st,
                             float* __restrict__ h0, int N) {
    __shared__ int xs[4 * XCOLS];
    int node = blockIdx.x * 4 + (threadIdx.x >> 6);
    int d = threadIdx.x & 63;
    if (threadIdx.x < 4 * XCOLS) {
        int n2 = blockIdx.x * 4 + threadIdx.x / XCOLS;
        int c = threadIdx.x % XCOLS;
        xs[threadIdx.x] = (n2 < N) ? x[n2 * XCOLS + c] : 0;
    }
    __syncthreads();
    if (node >= N) return;
    const int* xr = &xs[(threadIdx.x >> 6) * XCOLS];
    int bi = xr[1] + 2 * xr[2] + 3 * xr[3];   // argmax of one-hot
    int g = xr[4];
    float f = 0.f;
#pragma unroll
    for (int j = 0; j < NSYMP; ++j) {
        int sj = xr[5 + j];
        f += st[(j * 3 + sj) * EMB + d];
    }
    float val = (bt[bi * EMB + d] + gt[g * EMB + d] + f * (1.f / 15.f)) * (1.f / 3.f);
    h0[node * EMB + d] = val;
}

// ---------------- dual GEMM v4: register weights + 2-node ILP ----------------
// lane d holds Wl[:,d], Wr[:,d] in 128 VGPRs. Per iteration a wave computes TWO
// consecutive nodes with interleaved FMA chains -> 2x memory-level parallelism
// on the wave-uniform h-row loads (R11: 1-node version was load-latency-bound
// at ~43us vs 10.4us VALU floor). unroll 2 keeps ~4 float4 in flight (~160
// VGPR, no spill at 3 waves/SIMD).
__global__ __launch_bounds__(256, 3)
void gemm_dual_kernel(const float* __restrict__ h,
                      const float* __restrict__ Wl, const float* __restrict__ bl,
                      const float* __restrict__ Wr, const float* __restrict__ br,
                      float* __restrict__ outL, float* __restrict__ outR, int N) {
    int lane = threadIdx.x & 63;
    int wv = threadIdx.x >> 6;
    float wl[EMB], wr[EMB];
#pragma unroll
    for (int k = 0; k < EMB; ++k) {
        wl[k] = Wl[k * EMB + lane];
        wr[k] = Wr[k * EMB + lane];
    }
    float blv = bl[lane], brv = br[lane];
    int pstride = gridDim.x * 4;
    for (int pr = blockIdx.x * 4 + wv; pr * 2 < N; pr += pstride) {
        int nA = __builtin_amdgcn_readfirstlane(pr * 2);
        int nB = nA + 1;
        bool hasB = nB < N;
        const float* ra = h + (size_t)nA * EMB;
        const float* rb = h + (size_t)(hasB ? nB : nA) * EMB;
        float lA0 = blv, lA1 = 0.f, rA0 = brv, rA1 = 0.f;
        float lB0 = blv, lB1 = 0.f, rB0 = brv, rB1 = 0.f;
#pragma unroll 2
        for (int kk = 0; kk < EMB / 4; ++kk) {
            float4 ha = *(const float4*)(ra + kk * 4);
            float4 hb = *(const float4*)(rb + kk * 4);
            lA0 = fmaf(ha.x, wl[kk * 4 + 0], lA0);
            rA0 = fmaf(ha.x, wr[kk * 4 + 0], rA0);
            lB0 = fmaf(hb.x, wl[kk * 4 + 0], lB0);
            rB0 = fmaf(hb.x, wr[kk * 4 + 0], rB0);
            lA1 = fmaf(ha.y, wl[kk * 4 + 1], lA1);
            rA1 = fmaf(ha.y, wr[kk * 4 + 1], rA1);
            lB1 = fmaf(hb.y, wl[kk * 4 + 1], lB1);
            rB1 = fmaf(hb.y, wr[kk * 4 + 1], rB1);
            lA0 = fmaf(ha.z, wl[kk * 4 + 2], lA0);
            rA0 = fmaf(ha.z, wr[kk * 4 + 2], rA0);
            lB0 = fmaf(hb.z, wl[kk * 4 + 2], lB0);
            rB0 = fmaf(hb.z, wr[kk * 4 + 2], rB0);
            lA1 = fmaf(ha.w, wl[kk * 4 + 3], lA1);
            rA1 = fmaf(ha.w, wr[kk * 4 + 3], rA1);
            lB1 = fmaf(hb.w, wl[kk * 4 + 3], lB1);
            rB1 = fmaf(hb.w, wr[kk * 4 + 3], rB1);
        }
        outL[(size_t)nA * EMB + lane] = lA0 + lA1;
        outR[(size_t)nA * EMB + lane] = rA0 + rA1;
        if (hasB) {
            outL[(size_t)nB * EMB + lane] = lB0 + lB1;
            outR[(size_t)nB * EMB + lane] = rB0 + rB1;
        }
    }
}

// ---------------- CSR build via 2-level radix partition ----------------
// (bincount/bscan/partition operate on EDGES only; finalize inserts the
// self-loop as slot 0 of every node, so gat needs no special-casing.)
__global__ void bincount_kernel(const int* __restrict__ ei, int* __restrict__ bcount,
                                int* __restrict__ offs, int E, int NB, int N) {
    __shared__ int lh[MAXNB];
    for (int j = threadIdx.x; j < NB; j += 256) lh[j] = 0;
    __syncthreads();
    for (int i = blockIdx.x * 256 + threadIdx.x; i < E; i += gridDim.x * 256)
        atomicAdd(&lh[ei[E + i] >> BSH], 1);
    __syncthreads();
    for (int j = threadIdx.x; j < NB; j += 256)
        if (lh[j]) atomicAdd(&bcount[j], lh[j]);
    if (blockIdx.x == 0 && threadIdx.x == 0) offs[N] = E + N;   // slots incl. selfs
}

__global__ void bscan_kernel(const int* __restrict__ bcount, int* __restrict__ boffs,
                             int* __restrict__ bcursor, int NB) {
    __shared__ int s[1024];
    int t = threadIdx.x;
    int v0 = (t < NB) ? bcount[t] : 0;
    s[t] = v0;
    __syncthreads();
    for (int off = 1; off < 1024; off <<= 1) {
        int v = (t >= off) ? s[t - off] : 0;
        __syncthreads();
        s[t] += v;
        __syncthreads();
    }
    if (t < NB) {
        boffs[t + 1] = s[t];
        bcursor[t] = s[t] - v0;
    }
    if (t == 0) boffs[0] = 0;
}

__global__ void partition_kernel(const int* __restrict__ ei, int* __restrict__ bcursor,
                                 int* __restrict__ epart, int E, int NB) {
    __shared__ int lh[MAXNB];
    for (int j = threadIdx.x; j < NB; j += 256) lh[j] = 0;
    __syncthreads();
    int base = blockIdx.x * PCHUNK;
    int end = min(E, base + PCHUNK);
    for (int i = base + threadIdx.x; i < end; i += 256)
        atomicAdd(&lh[ei[E + i] >> BSH], 1);
    __syncthreads();
    for (int j = threadIdx.x; j < NB; j += 256) {
        int c = lh[j];
        lh[j] = c ? atomicAdd(&bcursor[j], c) : 0;
    }
    __syncthreads();
    for (int i = base + threadIdx.x; i < end; i += 256) {
        int dst = ei[E + i];
        int src = ei[i];
        int slot = atomicAdd(&lh[dst >> BSH], 1);
        epart[slot] = (src << BSH) | (dst & (BSZ - 1));
    }
}

// finalize: per-wave sub-histograms; node n gets deg+1 slots, slot 0 = self.
// slot base = edge_base(r0) + nodes_before_bucket(b*128) + edge_scan + t.
__global__ void finalize_kernel(const int* __restrict__ epart, const int* __restrict__ boffs,
                                int* __restrict__ offs, int* __restrict__ ssrc, int N) {
    __shared__ int deg4[4][BSZ];
    __shared__ int pos[BSZ];
    __shared__ int cur4[4][BSZ];
    int b = blockIdx.x;
    int t = threadIdx.x;
    int w = t >> 6;
    int n0 = b << BSH;
    int r0 = boffs[b], r1 = boffs[b + 1];
    ((int*)deg4)[t] = 0;
    ((int*)deg4)[t + 256] = 0;
    __syncthreads();
    for (int e = r0 + t; e < r1; e += 256)
        atomicAdd(&deg4[w][epart[e] & (BSZ - 1)], 1);
    __syncthreads();
    int d0 = 0, d1 = 0, d2 = 0, sum = 0;
    if (t < BSZ) {
        d0 = deg4[0][t]; d1 = deg4[1][t]; d2 = deg4[2][t];
        sum = d0 + d1 + d2 + deg4[3][t];
        pos[t] = sum;
    }
    __syncthreads();
    for (int off = 1; off < BSZ; off <<= 1) {
        int v = (t < BSZ && t >= off) ? pos[t - off] : 0;
        __syncthreads();
        if (t < BSZ) pos[t] += v;
        __syncthreads();
    }
    if (t < BSZ) {
        int node = n0 + t;
        int base = r0 + n0 + (pos[t] - sum) + t;   // edges + self-slots before node
        if (node < N) {
            offs[node] = base;
            ssrc[base] = node;                     // self-loop at slot 0
        }
        cur4[0][t] = base + 1;
        cur4[1][t] = base + 1 + d0;
        cur4[2][t] = base + 1 + d0 + d1;
        cur4[3][t] = base + 1 + d0 + d1 + d2;
    }
    __syncthreads();
    for (int e = r0 + t; e < r1; e += 256) {
        int v = epart[e];
        int s = atomicAdd(&cur4[w][v & (BSZ - 1)], 1);
        ssrc[s] = v >> BSH;
    }
}

// ---------------- DPP cross-lane add (VALU pipe; compiler handles hazards) --
template <int CTRL>
__device__ __forceinline__ float dpp_add(float v) {
    union { float f; int i; } u, r;
    u.f = v;
    r.i = __builtin_amdgcn_update_dpp(0, u.i, CTRL, 0xF, 0xF, true);
    return v + r.f;
}

// ---------------- GATv2 layer: 8 edges per wave iteration, pipelined --------
// Self-loop is a real CSR edge now (finalize inserts it) -> no special block.
template <int L>
__global__ void gat_kernel(const float* __restrict__ xl, const float* __restrict__ xr,
                           const int* __restrict__ offs, const int* __restrict__ ssrc,
                           const float* __restrict__ att, const float* __restrict__ bias,
                           const float* __restrict__ linW, const float* __restrict__ linb,
                           float* __restrict__ out, int N) {
    int wid = blockIdx.x * 4 + (threadIdx.x >> 6);
    int lane = threadIdx.x & 63;
    if (wid >= N) return;
    int grp = lane >> 4;          // edge slot within the 4-wide half-batch
    int li = lane & 15;           // float4 channel slot
    unsigned cb = (unsigned)li << 2;

    const float LOG2E = 1.4426950408889634f;
    float4 att4 = *(const float4*)(att + cb);
    att4.x *= LOG2E; att4.y *= LOG2E; att4.z *= LOG2E; att4.w *= LOG2E;
    float4 bias4 = *(const float4*)(bias + cb);
    unsigned rb = (unsigned)wid << 6;
    float4 xr4 = *(const float4*)(xr + rb + cb);

    int e0 = offs[wid], e1 = offs[wid + 1];

    float s = 0.f;
    float4 acc = {0.f, 0.f, 0.f, 0.f};

    // prologue: indices for first batch (ssrc padded -> unconditional loads OK)
    unsigned sA = (unsigned)ssrc[e0 + grp];
    unsigned sB = (unsigned)ssrc[e0 + 4 + grp];
    sA = (e0 + grp < e1) ? sA : (unsigned)wid;
    sB = (e0 + 4 + grp < e1) ? sB : (unsigned)wid;

    for (int t = e0; t < e1; t += 8) {
        float4 a = *(const float4*)(xl + (sA << 6) + cb);
        float4 b = *(const float4*)(xl + (sB << 6) + cb);
        int tn = t + 8;
        unsigned nA = (unsigned)ssrc[tn + grp];
        unsigned nB = (unsigned)ssrc[tn + 4 + grp];
        nA = (tn + grp < e1) ? nA : (unsigned)wid;
        nB = (tn + 4 + grp < e1) ? nB : (unsigned)wid;
        bool vA = t + grp < e1;
        bool vB = t + 4 + grp < e1;

        float ux = a.x + xr4.x; ux = fmaxf(ux, 0.2f * ux);
        float uy = a.y + xr4.y; uy = fmaxf(uy, 0.2f * uy);
        float uz = a.z + xr4.z; uz = fmaxf(uz, 0.2f * uz);
        float uw = a.w + xr4.w; uw = fmaxf(uw, 0.2f * uw);
        float pa = att4.x * ux + att4.y * uy + att4.z * uz + att4.w * uw;
        pa = dpp_add<0xB1>(pa);
        pa = dpp_add<0x4E>(pa);
        if (L == 2) {
            pa = dpp_add<0x141>(pa);
            pa = dpp_add<0x140>(pa);
        }
        float pA = exp2f(pa);
        pA = vA ? pA : 0.f;
        s += pA;
        acc.x += pA * a.x; acc.y += pA * a.y; acc.z += pA * a.z; acc.w += pA * a.w;

        float vx = b.x + xr4.x; vx = fmaxf(vx, 0.2f * vx);
        float vy = b.y + xr4.y; vy = fmaxf(vy, 0.2f * vy);
        float vz = b.z + xr4.z; vz = fmaxf(vz, 0.2f * vz);
        float vw = b.w + xr4.w; vw = fmaxf(vw, 0.2f * vw);
        float pb = att4.x * vx + att4.y * vy + att4.z * vz + att4.w * vw;
        pb = dpp_add<0xB1>(pb);
        pb = dpp_add<0x4E>(pb);
        if (L == 2) {
            pb = dpp_add<0x141>(pb);
            pb = dpp_add<0x140>(pb);
        }
        float pB = exp2f(pb);
        pB = vB ? pB : 0.f;
        s += pB;
        acc.x += pB * b.x; acc.y += pB * b.y; acc.z += pB * b.z; acc.w += pB * b.w;

        sA = nA; sB = nB;
    }

    // combine the 4 edge groups (once per node)
    s += __shfl_xor(s, 16); s += __shfl_xor(s, 32);
    acc.x += __shfl_xor(acc.x, 16); acc.x += __shfl_xor(acc.x, 32);
    acc.y += __shfl_xor(acc.y, 16); acc.y += __shfl_xor(acc.y, 32);
    acc.z += __shfl_xor(acc.z, 16); acc.z += __shfl_xor(acc.z, 32);
    acc.w += __shfl_xor(acc.w, 16); acc.w += __shfl_xor(acc.w, 32);

    float inv = 1.f / (s + 1e-16f);
    if (L == 1) {
        float4 val;
        val.x = acc.x * inv + bias4.x;
        val.y = acc.y * inv + bias4.y;
        val.z = acc.z * inv + bias4.z;
        val.w = acc.w * inv + bias4.w;
        val.x = (val.x > 0.f) ? val.x : (__expf(val.x) - 1.f);
        val.y = (val.y > 0.f) ? val.y : (__expf(val.y) - 1.f);
        val.z = (val.z > 0.f) ? val.z : (__expf(val.z) - 1.f);
        val.w = (val.w > 0.f) ? val.w : (__expf(val.w) - 1.f);
        if (grp == 0) *(float4*)(out + rb + cb) = val;
    } else {
        float4 lw = *(const float4*)(linW + cb);
        float r = (acc.x * inv + bias4.x) * lw.x + (acc.y * inv + bias4.y) * lw.y +
                  (acc.z * inv + bias4.z) * lw.z + (acc.w * inv + bias4.w) * lw.w;
        r = dpp_add<0xB1>(r);
        r = dpp_add<0x4E>(r);
        r = dpp_add<0x141>(r);
        r = dpp_add<0x140>(r);
        if (lane == 0) out[wid] = r + linb[0];
    }
}

extern "C" void kernel_launch(void* const* d_in, const int* in_sizes, int n_in,
                              void* d_out, int out_size, void* d_ws, size_t ws_size,
                              hipStream_t stream) {
    const int* x = (const int*)d_in[0];
    const int* ei = (const int*)d_in[1];          // int32 marshalled
    const float* birth_tab = (const float*)d_in[2];
    const float* gender_tab = (const float*)d_in[3];
    const float* symp_tab = (const float*)d_in[4];
    const float* Wl1 = (const float*)d_in[5];
    const float* bl1 = (const float*)d_in[6];
    const float* Wr1 = (const float*)d_in[7];
    const float* br1 = (const float*)d_in[8];
    const float* att1 = (const float*)d_in[9];
    const float* bias1 = (const float*)d_in[10];
    const float* Wl2 = (const float*)d_in[11];
    const float* bl2 = (const float*)d_in[12];
    const float* Wr2 = (const float*)d_in[13];
    const float* br2 = (const float*)d_in[14];
    const float* att2 = (const float*)d_in[15];
    const float* bias2 = (const float*)d_in[16];
    const float* linW = (const float*)d_in[17];
    const float* linb = (const float*)d_in[18];
    float* outp = (float*)d_out;

    int N = in_sizes[0] / XCOLS;   // 100000
    int E = in_sizes[1] / 2;       // 1600000
    int NB = (N + BSZ - 1) >> BSH; // 782

    char* p = (char*)d_ws;
    auto alloc = [&](size_t bytes) {
        void* r = (void*)p;
        p += (bytes + 255) & ~(size_t)255;
        return r;
    };
    float* h0 = (float*)alloc((size_t)N * EMB * 4);
    float* bufA = (float*)alloc((size_t)N * EMB * 4);
    float* bufB = (float*)alloc((size_t)N * EMB * 4);
    int* bcount = (int*)alloc(MAXNB * 4);
    int* boffs = (int*)alloc((MAXNB + 1) * 4);
    int* bcursor = (int*)alloc(MAXNB * 4);
    int* offs = (int*)alloc((size_t)(N + 1) * 4);
    int* epart = (int*)alloc((size_t)E * 4);
    int* ssrc = (int*)alloc((size_t)(E + N + 64) * 4);  // edges + selfs + pad

    int ngrp = (N + 3) / 4;

    // CSR build (2-level radix partition; self-loops added in finalize)
    zero_kernel<<<(NB + 255) / 256, 256, 0, stream>>>(bcount, NB);
    bincount_kernel<<<512, 256, 0, stream>>>(ei, bcount, offs, E, NB, N);
    bscan_kernel<<<1, 1024, 0, stream>>>(bcount, boffs, bcursor, NB);
    partition_kernel<<<(E + PCHUNK - 1) / PCHUNK, 256, 0, stream>>>(ei, bcursor, epart, E, NB);
    finalize_kernel<<<NB, 256, 0, stream>>>(epart, boffs, offs, ssrc, N);

    // node pipeline
    embed_kernel<<<ngrp, 256, 0, stream>>>(x, birth_tab, gender_tab, symp_tab, h0, N);
    gemm_dual_kernel<<<768, 256, 0, stream>>>(h0, Wl1, bl1, Wr1, br1, bufA, bufB, N);
    gat_kernel<1><<<ngrp, 256, 0, stream>>>(bufA, bufB, offs, ssrc, att1, bias1,
                                            nullptr, nullptr, h0, N);
    gemm_dual_kernel<<<768, 256, 0, stream>>>(h0, Wl2, bl2, Wr2, br2, bufA, bufB, N);
    gat_kernel<2><<<ngrp, 256, 0, stream>>>(bufA, bufB, offs, ssrc, att2, bias2,
                                            linW, linb, outp, N);
}

// Round 13
// 293.603 us; speedup vs baseline: 2.3716x; 2.3716x over previous
//
#include <hip/hip_runtime.h>
#include <hip/hip_bf16.h>

#define EMB 64
#define XCOLS 20
#define NSYMP 15
#define BSH 7
#define BSZ 128          // nodes per bucket (1<<BSH)
#define MAXNB 1024       // supports N <= 131072
#define PCHUNK 4096

__global__ void zero_kernel(int* __restrict__ p, int n) {
    int i = blockIdx.x * blockDim.x + threadIdx.x;
    if (i < n) p[i] = 0;
}

// ---------------- embedding ----------------
__global__ void embed_kernel(const int* __restrict__ x,
                             const float* __restrict__ bt,
                             const float* __restrict__ gt,
                             const float* __restrict__ st,
                             float* __restrict__ h0, int N) {
    __shared__ int xs[4 * XCOLS];
    int node = blockIdx.x * 4 + (threadIdx.x >> 6);
    int d = threadIdx.x & 63;
    if (threadIdx.x < 4 * XCOLS) {
        int n2 = blockIdx.x * 4 + threadIdx.x / XCOLS;
        int c = threadIdx.x % XCOLS;
        xs[threadIdx.x] = (n2 < N) ? x[n2 * XCOLS + c] : 0;
    }
    __syncthreads();
    if (node >= N) return;
    const int* xr = &xs[(threadIdx.x >> 6) * XCOLS];
    int bi = xr[1] + 2 * xr[2] + 3 * xr[3];   // argmax of one-hot
    int g = xr[4];
    float f = 0.f;
#pragma unroll
    for (int j = 0; j < NSYMP; ++j) {
        int sj = xr[5 + j];
        f += st[(j * 3 + sj) * EMB + d];
    }
    float val = (bt[bi * EMB + d] + gt[g * EMB + d] + f * (1.f / 15.f)) * (1.f / 3.f);
    h0[node * EMB + d] = val;
}

// ---------------- dual GEMM v5: register weights + 2-node ILP, FULL unroll ----
// R12 lesson (rule #20): "#pragma unroll 2" made wl[]/wr[] indices runtime ->
// arrays went to SCRATCH (VGPR=32, FETCH 779MB, 9% VALU). v5 fully unrolls so
// every index is compile-time constant (mem2reg -> registers), keeps 2-node
// ILP for memory-level parallelism, and __launch_bounds__(256,2) gives a
// 256-VGPR budget (128 weights + 16 acc + in-flight loads, no spill).
__global__ __launch_bounds__(256, 2)
void gemm_dual_kernel(const float* __restrict__ h,
                      const float* __restrict__ Wl, const float* __restrict__ bl,
                      const float* __restrict__ Wr, const float* __restrict__ br,
                      float* __restrict__ outL, float* __restrict__ outR, int N) {
    int lane = threadIdx.x & 63;
    int wv = threadIdx.x >> 6;
    float wl[EMB], wr[EMB];
#pragma unroll
    for (int k = 0; k < EMB; ++k) {
        wl[k] = Wl[k * EMB + lane];
        wr[k] = Wr[k * EMB + lane];
    }
    float blv = bl[lane], brv = br[lane];
    int pstride = gridDim.x * 4;
    int npairs = (N + 1) >> 1;
    for (int pr = blockIdx.x * 4 + wv; pr < npairs; pr += pstride) {
        int nA = __builtin_amdgcn_readfirstlane(pr * 2);
        int nB = nA + 1;
        bool hasB = nB < N;
        const float* ra = h + (size_t)nA * EMB;
        const float* rb = h + (size_t)(hasB ? nB : nA) * EMB;
        float lA0 = blv, lA1 = 0.f, rA0 = brv, rA1 = 0.f;
        float lB0 = blv, lB1 = 0.f, rB0 = brv, rB1 = 0.f;
#pragma unroll
        for (int kk = 0; kk < EMB / 4; ++kk) {
            float4 ha = *(const float4*)(ra + kk * 4);
            float4 hb = *(const float4*)(rb + kk * 4);
            lA0 = fmaf(ha.x, wl[kk * 4 + 0], lA0);
            rA0 = fmaf(ha.x, wr[kk * 4 + 0], rA0);
            lB0 = fmaf(hb.x, wl[kk * 4 + 0], lB0);
            rB0 = fmaf(hb.x, wr[kk * 4 + 0], rB0);
            lA1 = fmaf(ha.y, wl[kk * 4 + 1], lA1);
            rA1 = fmaf(ha.y, wr[kk * 4 + 1], rA1);
            lB1 = fmaf(hb.y, wl[kk * 4 + 1], lB1);
            rB1 = fmaf(hb.y, wr[kk * 4 + 1], rB1);
            lA0 = fmaf(ha.z, wl[kk * 4 + 2], lA0);
            rA0 = fmaf(ha.z, wr[kk * 4 + 2], rA0);
            lB0 = fmaf(hb.z, wl[kk * 4 + 2], lB0);
            rB0 = fmaf(hb.z, wr[kk * 4 + 2], rB0);
            lA1 = fmaf(ha.w, wl[kk * 4 + 3], lA1);
            rA1 = fmaf(ha.w, wr[kk * 4 + 3], rA1);
            lB1 = fmaf(hb.w, wl[kk * 4 + 3], lB1);
            rB1 = fmaf(hb.w, wr[kk * 4 + 3], rB1);
        }
        outL[(size_t)nA * EMB + lane] = lA0 + lA1;
        outR[(size_t)nA * EMB + lane] = rA0 + rA1;
        if (hasB) {
            outL[(size_t)nB * EMB + lane] = lB0 + lB1;
            outR[(size_t)nB * EMB + lane] = rB0 + rB1;
        }
    }
}

// ---------------- CSR build via 2-level radix partition ----------------
// (bincount/bscan/partition operate on EDGES only; finalize inserts the
// self-loop as slot 0 of every node, so gat needs no special-casing.)
__global__ void bincount_kernel(const int* __restrict__ ei, int* __restrict__ bcount,
                                int* __restrict__ offs, int E, int NB, int N) {
    __shared__ int lh[MAXNB];
    for (int j = threadIdx.x; j < NB; j += 256) lh[j] = 0;
    __syncthreads();
    for (int i = blockIdx.x * 256 + threadIdx.x; i < E; i += gridDim.x * 256)
        atomicAdd(&lh[ei[E + i] >> BSH], 1);
    __syncthreads();
    for (int j = threadIdx.x; j < NB; j += 256)
        if (lh[j]) atomicAdd(&bcount[j], lh[j]);
    if (blockIdx.x == 0 && threadIdx.x == 0) offs[N] = E + N;   // slots incl. selfs
}

__global__ void bscan_kernel(const int* __restrict__ bcount, int* __restrict__ boffs,
                             int* __restrict__ bcursor, int NB) {
    __shared__ int s[1024];
    int t = threadIdx.x;
    int v0 = (t < NB) ? bcount[t] : 0;
    s[t] = v0;
    __syncthreads();
    for (int off = 1; off < 1024; off <<= 1) {
        int v = (t >= off) ? s[t - off] : 0;
        __syncthreads();
        s[t] += v;
        __syncthreads();
    }
    if (t < NB) {
        boffs[t + 1] = s[t];
        bcursor[t] = s[t] - v0;
    }
    if (t == 0) boffs[0] = 0;
}

__global__ void partition_kernel(const int* __restrict__ ei, int* __restrict__ bcursor,
                                 int* __restrict__ epart, int E, int NB) {
    __shared__ int lh[MAXNB];
    for (int j = threadIdx.x; j < NB; j += 256) lh[j] = 0;
    __syncthreads();
    int base = blockIdx.x * PCHUNK;
    int end = min(E, base + PCHUNK);
    for (int i = base + threadIdx.x; i < end; i += 256)
        atomicAdd(&lh[ei[E + i] >> BSH], 1);
    __syncthreads();
    for (int j = threadIdx.x; j < NB; j += 256) {
        int c = lh[j];
        lh[j] = c ? atomicAdd(&bcursor[j], c) : 0;
    }
    __syncthreads();
    for (int i = base + threadIdx.x; i < end; i += 256) {
        int dst = ei[E + i];
        int src = ei[i];
        int slot = atomicAdd(&lh[dst >> BSH], 1);
        epart[slot] = (src << BSH) | (dst & (BSZ - 1));
    }
}

// finalize: per-wave sub-histograms; node n gets deg+1 slots, slot 0 = self.
__global__ void finalize_kernel(const int* __restrict__ epart, const int* __restrict__ boffs,
                                int* __restrict__ offs, int* __restrict__ ssrc, int N) {
    __shared__ int deg4[4][BSZ];
    __shared__ int pos[BSZ];
    __shared__ int cur4[4][BSZ];
    int b = blockIdx.x;
    int t = threadIdx.x;
    int w = t >> 6;
    int n0 = b << BSH;
    int r0 = boffs[b], r1 = boffs[b + 1];
    ((int*)deg4)[t] = 0;
    ((int*)deg4)[t + 256] = 0;
    __syncthreads();
    for (int e = r0 + t; e < r1; e += 256)
        atomicAdd(&deg4[w][epart[e] & (BSZ - 1)], 1);
    __syncthreads();
    int d0 = 0, d1 = 0, d2 = 0, sum = 0;
    if (t < BSZ) {
        d0 = deg4[0][t]; d1 = deg4[1][t]; d2 = deg4[2][t];
        sum = d0 + d1 + d2 + deg4[3][t];
        pos[t] = sum;
    }
    __syncthreads();
    for (int off = 1; off < BSZ; off <<= 1) {
        int v = (t < BSZ && t >= off) ? pos[t - off] : 0;
        __syncthreads();
        if (t < BSZ) pos[t] += v;
        __syncthreads();
    }
    if (t < BSZ) {
        int node = n0 + t;
        int base = r0 + n0 + (pos[t] - sum) + t;   // edges + self-slots before node
        if (node < N) {
            offs[node] = base;
            ssrc[base] = node;                     // self-loop at slot 0
        }
        cur4[0][t] = base + 1;
        cur4[1][t] = base + 1 + d0;
        cur4[2][t] = base + 1 + d0 + d1;
        cur4[3][t] = base + 1 + d0 + d1 + d2;
    }
    __syncthreads();
    for (int e = r0 + t; e < r1; e += 256) {
        int v = epart[e];
        int s = atomicAdd(&cur4[w][v & (BSZ - 1)], 1);
        ssrc[s] = v >> BSH;
    }
}

// ---------------- DPP cross-lane add (VALU pipe; compiler handles hazards) --
template <int CTRL>
__device__ __forceinline__ float dpp_add(float v) {
    union { float f; int i; } u, r;
    u.f = v;
    r.i = __builtin_amdgcn_update_dpp(0, u.i, CTRL, 0xF, 0xF, true);
    return v + r.f;
}

// ---------------- GATv2 layer: 8 edges per wave iteration, pipelined --------
// Self-loop is a real CSR edge (finalize inserts it) -> no special block.
template <int L>
__global__ void gat_kernel(const float* __restrict__ xl, const float* __restrict__ xr,
                           const int* __restrict__ offs, const int* __restrict__ ssrc,
                           const float* __restrict__ att, const float* __restrict__ bias,
                           const float* __restrict__ linW, const float* __restrict__ linb,
                           float* __restrict__ out, int N) {
    int wid = blockIdx.x * 4 + (threadIdx.x >> 6);
    int lane = threadIdx.x & 63;
    if (wid >= N) return;
    int grp = lane >> 4;          // edge slot within the 4-wide half-batch
    int li = lane & 15;           // float4 channel slot
    unsigned cb = (unsigned)li << 2;

    const float LOG2E = 1.4426950408889634f;
    float4 att4 = *(const float4*)(att + cb);
    att4.x *= LOG2E; att4.y *= LOG2E; att4.z *= LOG2E; att4.w *= LOG2E;
    float4 bias4 = *(const float4*)(bias + cb);
    unsigned rb = (unsigned)wid << 6;
    float4 xr4 = *(const float4*)(xr + rb + cb);

    int e0 = offs[wid], e1 = offs[wid + 1];

    float s = 0.f;
    float4 acc = {0.f, 0.f, 0.f, 0.f};

    // prologue: indices for first batch (ssrc padded -> unconditional loads OK)
    unsigned sA = (unsigned)ssrc[e0 + grp];
    unsigned sB = (unsigned)ssrc[e0 + 4 + grp];
    sA = (e0 + grp < e1) ? sA : (unsigned)wid;
    sB = (e0 + 4 + grp < e1) ? sB : (unsigned)wid;

    for (int t = e0; t < e1; t += 8) {
        float4 a = *(const float4*)(xl + (sA << 6) + cb);
        float4 b = *(const float4*)(xl + (sB << 6) + cb);
        int tn = t + 8;
        unsigned nA = (unsigned)ssrc[tn + grp];
        unsigned nB = (unsigned)ssrc[tn + 4 + grp];
        nA = (tn + grp < e1) ? nA : (unsigned)wid;
        nB = (tn + 4 + grp < e1) ? nB : (unsigned)wid;
        bool vA = t + grp < e1;
        bool vB = t + 4 + grp < e1;

        float ux = a.x + xr4.x; ux = fmaxf(ux, 0.2f * ux);
        float uy = a.y + xr4.y; uy = fmaxf(uy, 0.2f * uy);
        float uz = a.z + xr4.z; uz = fmaxf(uz, 0.2f * uz);
        float uw = a.w + xr4.w; uw = fmaxf(uw, 0.2f * uw);
        float pa = att4.x * ux + att4.y * uy + att4.z * uz + att4.w * uw;
        pa = dpp_add<0xB1>(pa);
        pa = dpp_add<0x4E>(pa);
        if (L == 2) {
            pa = dpp_add<0x141>(pa);
            pa = dpp_add<0x140>(pa);
        }
        float pA = exp2f(pa);
        pA = vA ? pA : 0.f;
        s += pA;
        acc.x += pA * a.x; acc.y += pA * a.y; acc.z += pA * a.z; acc.w += pA * a.w;

        float vx = b.x + xr4.x; vx = fmaxf(vx, 0.2f * vx);
        float vy = b.y + xr4.y; vy = fmaxf(vy, 0.2f * vy);
        float vz = b.z + xr4.z; vz = fmaxf(vz, 0.2f * vz);
        float vw = b.w + xr4.w; vw = fmaxf(vw, 0.2f * vw);
        float pb = att4.x * vx + att4.y * vy + att4.z * vz + att4.w * vw;
        pb = dpp_add<0xB1>(pb);
        pb = dpp_add<0x4E>(pb);
        if (L == 2) {
            pb = dpp_add<0x141>(pb);
            pb = dpp_add<0x140>(pb);
        }
        float pB = exp2f(pb);
        pB = vB ? pB : 0.f;
        s += pB;
        acc.x += pB * b.x; acc.y += pB * b.y; acc.z += pB * b.z; acc.w += pB * b.w;

        sA = nA; sB = nB;
    }

    // combine the 4 edge groups (once per node)
    s += __shfl_xor(s, 16); s += __shfl_xor(s, 32);
    acc.x += __shfl_xor(acc.x, 16); acc.x += __shfl_xor(acc.x, 32);
    acc.y += __shfl_xor(acc.y, 16); acc.y += __shfl_xor(acc.y, 32);
    acc.z += __shfl_xor(acc.z, 16); acc.z += __shfl_xor(acc.z, 32);
    acc.w += __shfl_xor(acc.w, 16); acc.w += __shfl_xor(acc.w, 32);

    float inv = 1.f / (s + 1e-16f);
    if (L == 1) {
        float4 val;
        val.x = acc.x * inv + bias4.x;
        val.y = acc.y * inv + bias4.y;
        val.z = acc.z * inv + bias4.z;
        val.w = acc.w * inv + bias4.w;
        val.x = (val.x > 0.f) ? val.x : (__expf(val.x) - 1.f);
        val.y = (val.y > 0.f) ? val.y : (__expf(val.y) - 1.f);
        val.z = (val.z > 0.f) ? val.z : (__expf(val.z) - 1.f);
        val.w = (val.w > 0.f) ? val.w : (__expf(val.w) - 1.f);
        if (grp == 0) *(float4*)(out + rb + cb) = val;
    } else {
        float4 lw = *(const float4*)(linW + cb);
        float r = (acc.x * inv + bias4.x) * lw.x + (acc.y * inv + bias4.y) * lw.y +
                  (acc.z * inv + bias4.z) * lw.z + (acc.w * inv + bias4.w) * lw.w;
        r = dpp_add<0xB1>(r);
        r = dpp_add<0x4E>(r);
        r = dpp_add<0x141>(r);
        r = dpp_add<0x140>(r);
        if (lane == 0) out[wid] = r + linb[0];
    }
}

extern "C" void kernel_launch(void* const* d_in, const int* in_sizes, int n_in,
                              void* d_out, int out_size, void* d_ws, size_t ws_size,
                              hipStream_t stream) {
    const int* x = (const int*)d_in[0];
    const int* ei = (const int*)d_in[1];          // int32 marshalled
    const float* birth_tab = (const float*)d_in[2];
    const float* gender_tab = (const float*)d_in[3];
    const float* symp_tab = (const float*)d_in[4];
    const float* Wl1 = (const float*)d_in[5];
    const float* bl1 = (const float*)d_in[6];
    const float* Wr1 = (const float*)d_in[7];
    const float* br1 = (const float*)d_in[8];
    const float* att1 = (const float*)d_in[9];
    const float* bias1 = (const float*)d_in[10];
    const float* Wl2 = (const float*)d_in[11];
    const float* bl2 = (const float*)d_in[12];
    const float* Wr2 = (const float*)d_in[13];
    const float* br2 = (const float*)d_in[14];
    const float* att2 = (const float*)d_in[15];
    const float* bias2 = (const float*)d_in[16];
    const float* linW = (const float*)d_in[17];
    const float* linb = (const float*)d_in[18];
    float* outp = (float*)d_out;

    int N = in_sizes[0] / XCOLS;   // 100000
    int E = in_sizes[1] / 2;       // 1600000
    int NB = (N + BSZ - 1) >> BSH; // 782

    char* p = (char*)d_ws;
    auto alloc = [&](size_t bytes) {
        void* r = (void*)p;
        p += (bytes + 255) & ~(size_t)255;
        return r;
    };
    float* h0 = (float*)alloc((size_t)N * EMB * 4);
    float* bufA = (float*)alloc((size_t)N * EMB * 4);
    float* bufB = (float*)alloc((size_t)N * EMB * 4);
    int* bcount = (int*)alloc(MAXNB * 4);
    int* boffs = (int*)alloc((MAXNB + 1) * 4);
    int* bcursor = (int*)alloc(MAXNB * 4);
    int* offs = (int*)alloc((size_t)(N + 1) * 4);
    int* epart = (int*)alloc((size_t)E * 4);
    int* ssrc = (int*)alloc((size_t)(E + N + 64) * 4);  // edges + selfs + pad

    int ngrp = (N + 3) / 4;

    // CSR build (2-level radix partition; self-loops added in finalize)
    zero_kernel<<<(NB + 255) / 256, 256, 0, stream>>>(bcount, NB);
    bincount_kernel<<<512, 256, 0, stream>>>(ei, bcount, offs, E, NB, N);
    bscan_kernel<<<1, 1024, 0, stream>>>(bcount, boffs, bcursor, NB);
    partition_kernel<<<(E + PCHUNK - 1) / PCHUNK, 256, 0, stream>>>(ei, bcursor, epart, E, NB);
    finalize_kernel<<<NB, 256, 0, stream>>>(epart, boffs, offs, ssrc, N);

    // node pipeline
    embed_kernel<<<ngrp, 256, 0, stream>>>(x, birth_tab, gender_tab, symp_tab, h0, N);
    gemm_dual_kernel<<<1024, 256, 0, stream>>>(h0, Wl1, bl1, Wr1, br1, bufA, bufB, N);
    gat_kernel<1><<<ngrp, 256, 0, stream>>>(bufA, bufB, offs, ssrc, att1, bias1,
                                            nullptr, nullptr, h0, N);
    gemm_dual_kernel<<<1024, 256, 0, stream>>>(h0, Wl2, bl2, Wr2, br2, bufA, bufB, N);
    gat_kernel<2><<<ngrp, 256, 0, stream>>>(bufA, bufB, offs, ssrc, att2, bias2,
                                            linW, linb, outp, N);
}

// Round 14
// 279.732 us; speedup vs baseline: 2.4892x; 1.0496x over previous
//
#include <hip/hip_runtime.h>
#include <hip/hip_bf16.h>

#define EMB 64
#define XCOLS 20
#define NSYMP 15
#define BSH 7
#define BSZ 128          // nodes per bucket (1<<BSH)
#define MAXNB 1024       // supports N <= 131072
#define PCHUNK 4096
#define GTILE 16         // gemm nodes per block-tile

__global__ void zero_kernel(int* __restrict__ p, int n) {
    int i = blockIdx.x * blockDim.x + threadIdx.x;
    if (i < n) p[i] = 0;
}

// ---------------- embedding ----------------
__global__ void embed_kernel(const int* __restrict__ x,
                             const float* __restrict__ bt,
                             const float* __restrict__ gt,
                             const float* __restrict__ st,
                             float* __restrict__ h0, int N) {
    __shared__ int xs[4 * XCOLS];
    int node = blockIdx.x * 4 + (threadIdx.x >> 6);
    int d = threadIdx.x & 63;
    if (threadIdx.x < 4 * XCOLS) {
        int n2 = blockIdx.x * 4 + threadIdx.x / XCOLS;
        int c = threadIdx.x % XCOLS;
        xs[threadIdx.x] = (n2 < N) ? x[n2 * XCOLS + c] : 0;
    }
    __syncthreads();
    if (node >= N) return;
    const int* xr = &xs[(threadIdx.x >> 6) * XCOLS];
    int bi = xr[1] + 2 * xr[2] + 3 * xr[3];   // argmax of one-hot
    int g = xr[4];
    float f = 0.f;
#pragma unroll
    for (int j = 0; j < NSYMP; ++j) {
        int sj = xr[5 + j];
        f += st[(j * 3 + sj) * EMB + d];
    }
    float val = (bt[bi * EMB + d] + gt[g * EMB + d] + f * (1.f / 15.f)) * (1.f / 3.f);
    h0[node * EMB + d] = val;
}

// ---------------- dual GEMM v6: LDS-broadcast h + register weights ----------
// lane d holds Wl[:,d], Wr[:,d] in 128 VGPRs (full unroll -> true registers,
// rule #20). Block stages a 16-node h tile into LDS with ONE coalesced float4
// load/thread (double-buffered, 8KB); each wave reads its 4 nodes' rows as
// uniform ds_read_b128 broadcasts (~120cyc, pipelined) instead of the 16
// serial ~300cyc global loads that made v3/v5 latency-bound (43-50us vs the
// 10.4us VALU floor). Per node: 16 ds_read + 128 FMA -> VALU-bound.
__global__ __launch_bounds__(256, 2)
void gemm_dual_kernel(const float* __restrict__ h,
                      const float* __restrict__ Wl, const float* __restrict__ bl,
                      const float* __restrict__ Wr, const float* __restrict__ br,
                      float* __restrict__ outL, float* __restrict__ outR, int N) {
    __shared__ float hs[2][GTILE][EMB];   // 8 KB
    int lane = threadIdx.x & 63;
    int wv = threadIdx.x >> 6;
    float wl[EMB], wr[EMB];
#pragma unroll
    for (int k = 0; k < EMB; ++k) {
        wl[k] = Wl[k * EMB + lane];
        wr[k] = Wr[k * EMB + lane];
    }
    float blv = bl[lane], brv = br[lane];
    int ntiles = (N + GTILE - 1) / GTILE;
    size_t total = (size_t)N * EMB;
    // preload tile 0
    if (blockIdx.x < ntiles) {
        size_t idx = (size_t)blockIdx.x * (GTILE * EMB) + threadIdx.x * 4;
        float4 v = {0.f, 0.f, 0.f, 0.f};
        if (idx + 3 < total) v = *(const float4*)(h + idx);
        else for (int j = 0; j < 4; ++j) ((float*)&v)[j] = (idx + j < total) ? h[idx + j] : 0.f;
        ((float4*)&hs[0][0][0])[threadIdx.x] = v;
    }
    int buf = 0;
    for (int g = blockIdx.x; g < ntiles; g += gridDim.x) {
        __syncthreads();                  // hs[buf] ready
        int gn = g + gridDim.x;
        if (gn < ntiles) {
            size_t idx = (size_t)gn * (GTILE * EMB) + threadIdx.x * 4;
            float4 v = {0.f, 0.f, 0.f, 0.f};
            if (idx + 3 < total) v = *(const float4*)(h + idx);
            else for (int j = 0; j < 4; ++j) ((float*)&v)[j] = (idx + j < total) ? h[idx + j] : 0.f;
            ((float4*)&hs[buf ^ 1][0][0])[threadIdx.x] = v;
        }
#pragma unroll
        for (int j = 0; j < 4; ++j) {
            int node = g * GTILE + wv * 4 + j;
            if (node < N) {
                const float* hp = &hs[buf][wv * 4 + j][0];
                float l0 = blv, l1 = 0.f, r0 = brv, r1 = 0.f;
#pragma unroll
                for (int kk = 0; kk < EMB / 4; ++kk) {
                    float4 hv = *(const float4*)(hp + kk * 4);
                    l0 = fmaf(hv.x, wl[kk * 4 + 0], l0);
                    r0 = fmaf(hv.x, wr[kk * 4 + 0], r0);
                    l1 = fmaf(hv.y, wl[kk * 4 + 1], l1);
                    r1 = fmaf(hv.y, wr[kk * 4 + 1], r1);
                    l0 = fmaf(hv.z, wl[kk * 4 + 2], l0);
                    r0 = fmaf(hv.z, wr[kk * 4 + 2], r0);
                    l1 = fmaf(hv.w, wl[kk * 4 + 3], l1);
                    r1 = fmaf(hv.w, wr[kk * 4 + 3], r1);
                }
                outL[(size_t)node * EMB + lane] = l0 + l1;
                outR[(size_t)node * EMB + lane] = r0 + r1;
            }
        }
        buf ^= 1;
    }
}

// ---------------- CSR build via 2-level radix partition ----------------
// (bincount/bscan/partition operate on EDGES only; finalize inserts the
// self-loop as slot 0 of every node, so gat needs no special-casing.)
__global__ void bincount_kernel(const int* __restrict__ ei, int* __restrict__ bcount,
                                int* __restrict__ offs, int E, int NB, int N) {
    __shared__ int lh[MAXNB];
    for (int j = threadIdx.x; j < NB; j += 256) lh[j] = 0;
    __syncthreads();
    for (int i = blockIdx.x * 256 + threadIdx.x; i < E; i += gridDim.x * 256)
        atomicAdd(&lh[ei[E + i] >> BSH], 1);
    __syncthreads();
    for (int j = threadIdx.x; j < NB; j += 256)
        if (lh[j]) atomicAdd(&bcount[j], lh[j]);
    if (blockIdx.x == 0 && threadIdx.x == 0) offs[N] = E + N;   // slots incl. selfs
}

__global__ void bscan_kernel(const int* __restrict__ bcount, int* __restrict__ boffs,
                             int* __restrict__ bcursor, int NB) {
    __shared__ int s[1024];
    int t = threadIdx.x;
    int v0 = (t < NB) ? bcount[t] : 0;
    s[t] = v0;
    __syncthreads();
    for (int off = 1; off < 1024; off <<= 1) {
        int v = (t >= off) ? s[t - off] : 0;
        __syncthreads();
        s[t] += v;
        __syncthreads();
    }
    if (t < NB) {
        boffs[t + 1] = s[t];
        bcursor[t] = s[t] - v0;
    }
    if (t == 0) boffs[0] = 0;
}

__global__ void partition_kernel(const int* __restrict__ ei, int* __restrict__ bcursor,
                                 int* __restrict__ epart, int E, int NB) {
    __shared__ int lh[MAXNB];
    for (int j = threadIdx.x; j < NB; j += 256) lh[j] = 0;
    __syncthreads();
    int base = blockIdx.x * PCHUNK;
    int end = min(E, base + PCHUNK);
    for (int i = base + threadIdx.x; i < end; i += 256)
        atomicAdd(&lh[ei[E + i] >> BSH], 1);
    __syncthreads();
    for (int j = threadIdx.x; j < NB; j += 256) {
        int c = lh[j];
        lh[j] = c ? atomicAdd(&bcursor[j], c) : 0;
    }
    __syncthreads();
    for (int i = base + threadIdx.x; i < end; i += 256) {
        int dst = ei[E + i];
        int src = ei[i];
        int slot = atomicAdd(&lh[dst >> BSH], 1);
        epart[slot] = (src << BSH) | (dst & (BSZ - 1));
    }
}

// finalize: per-wave sub-histograms; node n gets deg+1 slots, slot 0 = self.
__global__ void finalize_kernel(const int* __restrict__ epart, const int* __restrict__ boffs,
                                int* __restrict__ offs, int* __restrict__ ssrc, int N) {
    __shared__ int deg4[4][BSZ];
    __shared__ int pos[BSZ];
    __shared__ int cur4[4][BSZ];
    int b = blockIdx.x;
    int t = threadIdx.x;
    int w = t >> 6;
    int n0 = b << BSH;
    int r0 = boffs[b], r1 = boffs[b + 1];
    ((int*)deg4)[t] = 0;
    ((int*)deg4)[t + 256] = 0;
    __syncthreads();
    for (int e = r0 + t; e < r1; e += 256)
        atomicAdd(&deg4[w][epart[e] & (BSZ - 1)], 1);
    __syncthreads();
    int d0 = 0, d1 = 0, d2 = 0, sum = 0;
    if (t < BSZ) {
        d0 = deg4[0][t]; d1 = deg4[1][t]; d2 = deg4[2][t];
        sum = d0 + d1 + d2 + deg4[3][t];
        pos[t] = sum;
    }
    __syncthreads();
    for (int off = 1; off < BSZ; off <<= 1) {
        int v = (t < BSZ && t >= off) ? pos[t - off] : 0;
        __syncthreads();
        if (t < BSZ) pos[t] += v;
        __syncthreads();
    }
    if (t < BSZ) {
        int node = n0 + t;
        int base = r0 + n0 + (pos[t] - sum) + t;   // edges + self-slots before node
        if (node < N) {
            offs[node] = base;
            ssrc[base] = node;                     // self-loop at slot 0
        }
        cur4[0][t] = base + 1;
        cur4[1][t] = base + 1 + d0;
        cur4[2][t] = base + 1 + d0 + d1;
        cur4[3][t] = base + 1 + d0 + d1 + d2;
    }
    __syncthreads();
    for (int e = r0 + t; e < r1; e += 256) {
        int v = epart[e];
        int s = atomicAdd(&cur4[w][v & (BSZ - 1)], 1);
        ssrc[s] = v >> BSH;
    }
}

// ---------------- DPP cross-lane add (VALU pipe; compiler handles hazards) --
template <int CTRL>
__device__ __forceinline__ float dpp_add(float v) {
    union { float f; int i; } u, r;
    u.f = v;
    r.i = __builtin_amdgcn_update_dpp(0, u.i, CTRL, 0xF, 0xF, true);
    return v + r.f;
}

// ---------------- GATv2 layer: 8 edges per wave iteration, pipelined --------
// Self-loop is a real CSR edge (finalize inserts it) -> no special block.
template <int L>
__global__ void gat_kernel(const float* __restrict__ xl, const float* __restrict__ xr,
                           const int* __restrict__ offs, const int* __restrict__ ssrc,
                           const float* __restrict__ att, const float* __restrict__ bias,
                           const float* __restrict__ linW, const float* __restrict__ linb,
                           float* __restrict__ out, int N) {
    int wid = blockIdx.x * 4 + (threadIdx.x >> 6);
    int lane = threadIdx.x & 63;
    if (wid >= N) return;
    int grp = lane >> 4;          // edge slot within the 4-wide half-batch
    int li = lane & 15;           // float4 channel slot
    unsigned cb = (unsigned)li << 2;

    const float LOG2E = 1.4426950408889634f;
    float4 att4 = *(const float4*)(att + cb);
    att4.x *= LOG2E; att4.y *= LOG2E; att4.z *= LOG2E; att4.w *= LOG2E;
    float4 bias4 = *(const float4*)(bias + cb);
    unsigned rb = (unsigned)wid << 6;
    float4 xr4 = *(const float4*)(xr + rb + cb);

    int e0 = offs[wid], e1 = offs[wid + 1];

    float s = 0.f;
    float4 acc = {0.f, 0.f, 0.f, 0.f};

    // prologue: indices for first batch (ssrc padded -> unconditional loads OK)
    unsigned sA = (unsigned)ssrc[e0 + grp];
    unsigned sB = (unsigned)ssrc[e0 + 4 + grp];
    sA = (e0 + grp < e1) ? sA : (unsigned)wid;
    sB = (e0 + 4 + grp < e1) ? sB : (unsigned)wid;

    for (int t = e0; t < e1; t += 8) {
        float4 a = *(const float4*)(xl + (sA << 6) + cb);
        float4 b = *(const float4*)(xl + (sB << 6) + cb);
        int tn = t + 8;
        unsigned nA = (unsigned)ssrc[tn + grp];
        unsigned nB = (unsigned)ssrc[tn + 4 + grp];
        nA = (tn + grp < e1) ? nA : (unsigned)wid;
        nB = (tn + 4 + grp < e1) ? nB : (unsigned)wid;
        bool vA = t + grp < e1;
        bool vB = t + 4 + grp < e1;

        float ux = a.x + xr4.x; ux = fmaxf(ux, 0.2f * ux);
        float uy = a.y + xr4.y; uy = fmaxf(uy, 0.2f * uy);
        float uz = a.z + xr4.z; uz = fmaxf(uz, 0.2f * uz);
        float uw = a.w + xr4.w; uw = fmaxf(uw, 0.2f * uw);
        float pa = att4.x * ux + att4.y * uy + att4.z * uz + att4.w * uw;
        pa = dpp_add<0xB1>(pa);
        pa = dpp_add<0x4E>(pa);
        if (L == 2) {
            pa = dpp_add<0x141>(pa);
            pa = dpp_add<0x140>(pa);
        }
        float pA = exp2f(pa);
        pA = vA ? pA : 0.f;
        s += pA;
        acc.x += pA * a.x; acc.y += pA * a.y; acc.z += pA * a.z; acc.w += pA * a.w;

        float vx = b.x + xr4.x; vx = fmaxf(vx, 0.2f * vx);
        float vy = b.y + xr4.y; vy = fmaxf(vy, 0.2f * vy);
        float vz = b.z + xr4.z; vz = fmaxf(vz, 0.2f * vz);
        float vw = b.w + xr4.w; vw = fmaxf(vw, 0.2f * vw);
        float pb = att4.x * vx + att4.y * vy + att4.z * vz + att4.w * vw;
        pb = dpp_add<0xB1>(pb);
        pb = dpp_add<0x4E>(pb);
        if (L == 2) {
            pb = dpp_add<0x141>(pb);
            pb = dpp_add<0x140>(pb);
        }
        float pB = exp2f(pb);
        pB = vB ? pB : 0.f;
        s += pB;
        acc.x += pB * b.x; acc.y += pB * b.y; acc.z += pB * b.z; acc.w += pB * b.w;

        sA = nA; sB = nB;
    }

    // combine the 4 edge groups (once per node)
    s += __shfl_xor(s, 16); s += __shfl_xor(s, 32);
    acc.x += __shfl_xor(acc.x, 16); acc.x += __shfl_xor(acc.x, 32);
    acc.y += __shfl_xor(acc.y, 16); acc.y += __shfl_xor(acc.y, 32);
    acc.z += __shfl_xor(acc.z, 16); acc.z += __shfl_xor(acc.z, 32);
    acc.w += __shfl_xor(acc.w, 16); acc.w += __shfl_xor(acc.w, 32);

    float inv = 1.f / (s + 1e-16f);
    if (L == 1) {
        float4 val;
        val.x = acc.x * inv + bias4.x;
        val.y = acc.y * inv + bias4.y;
        val.z = acc.z * inv + bias4.z;
        val.w = acc.w * inv + bias4.w;
        val.x = (val.x > 0.f) ? val.x : (__expf(val.x) - 1.f);
        val.y = (val.y > 0.f) ? val.y : (__expf(val.y) - 1.f);
        val.z = (val.z > 0.f) ? val.z : (__expf(val.z) - 1.f);
        val.w = (val.w > 0.f) ? val.w : (__expf(val.w) - 1.f);
        if (grp == 0) *(float4*)(out + rb + cb) = val;
    } else {
        float4 lw = *(const float4*)(linW + cb);
        float r = (acc.x * inv + bias4.x) * lw.x + (acc.y * inv + bias4.y) * lw.y +
                  (acc.z * inv + bias4.z) * lw.z + (acc.w * inv + bias4.w) * lw.w;
        r = dpp_add<0xB1>(r);
        r = dpp_add<0x4E>(r);
        r = dpp_add<0x141>(r);
        r = dpp_add<0x140>(r);
        if (lane == 0) out[wid] = r + linb[0];
    }
}

extern "C" void kernel_launch(void* const* d_in, const int* in_sizes, int n_in,
                              void* d_out, int out_size, void* d_ws, size_t ws_size,
                              hipStream_t stream) {
    const int* x = (const int*)d_in[0];
    const int* ei = (const int*)d_in[1];          // int32 marshalled
    const float* birth_tab = (const float*)d_in[2];
    const float* gender_tab = (const float*)d_in[3];
    const float* symp_tab = (const float*)d_in[4];
    const float* Wl1 = (const float*)d_in[5];
    const float* bl1 = (const float*)d_in[6];
    const float* Wr1 = (const float*)d_in[7];
    const float* br1 = (const float*)d_in[8];
    const float* att1 = (const float*)d_in[9];
    const float* bias1 = (const float*)d_in[10];
    const float* Wl2 = (const float*)d_in[11];
    const float* bl2 = (const float*)d_in[12];
    const float* Wr2 = (const float*)d_in[13];
    const float* br2 = (const float*)d_in[14];
    const float* att2 = (const float*)d_in[15];
    const float* bias2 = (const float*)d_in[16];
    const float* linW = (const float*)d_in[17];
    const float* linb = (const float*)d_in[18];
    float* outp = (float*)d_out;

    int N = in_sizes[0] / XCOLS;   // 100000
    int E = in_sizes[1] / 2;       // 1600000
    int NB = (N + BSZ - 1) >> BSH; // 782

    char* p = (char*)d_ws;
    auto alloc = [&](size_t bytes) {
        void* r = (void*)p;
        p += (bytes + 255) & ~(size_t)255;
        return r;
    };
    float* h0 = (float*)alloc((size_t)N * EMB * 4);
    float* bufA = (float*)alloc((size_t)N * EMB * 4);
    float* bufB = (float*)alloc((size_t)N * EMB * 4);
    int* bcount = (int*)alloc(MAXNB * 4);
    int* boffs = (int*)alloc((MAXNB + 1) * 4);
    int* bcursor = (int*)alloc(MAXNB * 4);
    int* offs = (int*)alloc((size_t)(N + 1) * 4);
    int* epart = (int*)alloc((size_t)E * 4);
    int* ssrc = (int*)alloc((size_t)(E + N + 64) * 4);  // edges + selfs + pad

    int ngrp = (N + 3) / 4;

    // CSR build (2-level radix partition; self-loops added in finalize)
    zero_kernel<<<(NB + 255) / 256, 256, 0, stream>>>(bcount, NB);
    bincount_kernel<<<512, 256, 0, stream>>>(ei, bcount, offs, E, NB, N);
    bscan_kernel<<<1, 1024, 0, stream>>>(bcount, boffs, bcursor, NB);
    partition_kernel<<<(E + PCHUNK - 1) / PCHUNK, 256, 0, stream>>>(ei, bcursor, epart, E, NB);
    finalize_kernel<<<NB, 256, 0, stream>>>(epart, boffs, offs, ssrc, N);

    // node pipeline
    embed_kernel<<<ngrp, 256, 0, stream>>>(x, birth_tab, gender_tab, symp_tab, h0, N);
    gemm_dual_kernel<<<768, 256, 0, stream>>>(h0, Wl1, bl1, Wr1, br1, bufA, bufB, N);
    gat_kernel<1><<<ngrp, 256, 0, stream>>>(bufA, bufB, offs, ssrc, att1, bias1,
                                            nullptr, nullptr, h0, N);
    gemm_dual_kernel<<<768, 256, 0, stream>>>(h0, Wl2, bl2, Wr2, br2, bufA, bufB, N);
    gat_kernel<2><<<ngrp, 256, 0, stream>>>(bufA, bufB, offs, ssrc, att2, bias2,
                                            linW, linb, outp, N);
}

// Round 15
// 255.910 us; speedup vs baseline: 2.7209x; 1.0931x over previous
//
#include <hip/hip_runtime.h>
#include <hip/hip_bf16.h>

#define EMB 64
#define XCOLS 20
#define NSYMP 15
#define BSH 7
#define BSZ 128          // nodes per bucket (1<<BSH)
#define MAXNB 1024       // supports N <= 131072
#define PCHUNK 4096
#define GTILE 16         // gemm nodes per block-tile
#define TROWS 51         // 4 birth + 2 gender + 45 symp rows

__global__ void zero_kernel(int* __restrict__ p, int n) {
    int i = blockIdx.x * blockDim.x + threadIdx.x;
    if (i < n) p[i] = 0;
}

// ---------------- table transform: tL = table_row @ Wl, tR = table_row @ Wr --
// GEMM1 is linear in the embedding, and the embedding is a sum of rows from
// tiny tables (4+2+45 rows). Pre-transforming the tables (0.8 MFLOP) lets the
// embed gather produce xl/xr DIRECTLY -> deletes the 43us dense GEMM1 and the
// 51MB h0 round-trip entirely.
__global__ void transform_kernel(const float* __restrict__ bt,
                                 const float* __restrict__ gt,
                                 const float* __restrict__ st,
                                 const float* __restrict__ Wl,
                                 const float* __restrict__ Wr,
                                 float* __restrict__ tL, float* __restrict__ tR) {
    __shared__ float row[EMB];
    int r = blockIdx.x;          // 0..50
    int d = threadIdx.x;         // 64 threads
    const float* src = (r < 4) ? (bt + r * EMB)
                     : (r < 6) ? (gt + (r - 4) * EMB)
                               : (st + (r - 6) * EMB);
    row[d] = src[d];
    __syncthreads();
    float aL = 0.f, aR = 0.f;
#pragma unroll
    for (int k = 0; k < EMB; ++k) {
        float h = row[k];
        aL = fmaf(h, Wl[k * EMB + d], aL);
        aR = fmaf(h, Wr[k * EMB + d], aR);
    }
    tL[r * EMB + d] = aL;
    tR[r * EMB + d] = aR;
}

// ---------------- fused embed+GEMM1 via transformed tables ----------------
// xl[n][d] = (tL[bi][d] + tL[4+g][d] + (1/15) sum_j tL[6+j*3+sj][d]) / 3 + bl[d]
// Tables are 26KB total -> L1/L2 resident gathers.
__global__ void embedgemm_kernel(const int* __restrict__ x,
                                 const float* __restrict__ tL,
                                 const float* __restrict__ tR,
                                 const float* __restrict__ bl,
                                 const float* __restrict__ br,
                                 float* __restrict__ outL, float* __restrict__ outR,
                                 int N) {
    __shared__ int xs[4 * XCOLS];
    int node = blockIdx.x * 4 + (threadIdx.x >> 6);
    int d = threadIdx.x & 63;
    if (threadIdx.x < 4 * XCOLS) {
        int n2 = blockIdx.x * 4 + threadIdx.x / XCOLS;
        int c = threadIdx.x % XCOLS;
        xs[threadIdx.x] = (n2 < N) ? x[n2 * XCOLS + c] : 0;
    }
    __syncthreads();
    if (node >= N) return;
    const int* xr = &xs[(threadIdx.x >> 6) * XCOLS];
    int rbi = xr[1] + 2 * xr[2] + 3 * xr[3];   // birth row 0..3
    int rg = 4 + xr[4];                        // gender row 4..5
    float fL = 0.f, fR = 0.f;
#pragma unroll
    for (int j = 0; j < NSYMP; ++j) {
        int row = 6 + j * 3 + xr[5 + j];
        fL += tL[row * EMB + d];
        fR += tR[row * EMB + d];
    }
    float aL = (tL[rbi * EMB + d] + tL[rg * EMB + d] + fL * (1.f / 15.f)) * (1.f / 3.f) + bl[d];
    float aR = (tR[rbi * EMB + d] + tR[rg * EMB + d] + fR * (1.f / 15.f)) * (1.f / 3.f) + br[d];
    outL[node * EMB + d] = aL;
    outR[node * EMB + d] = aR;
}

// ---------------- dual GEMM v6 (layer 2 only): LDS h + register weights ----
__global__ __launch_bounds__(256, 2)
void gemm_dual_kernel(const float* __restrict__ h,
                      const float* __restrict__ Wl, const float* __restrict__ bl,
                      const float* __restrict__ Wr, const float* __restrict__ br,
                      float* __restrict__ outL, float* __restrict__ outR, int N) {
    __shared__ float hs[2][GTILE][EMB];   // 8 KB
    int lane = threadIdx.x & 63;
    int wv = threadIdx.x >> 6;
    float wl[EMB], wr[EMB];
#pragma unroll
    for (int k = 0; k < EMB; ++k) {
        wl[k] = Wl[k * EMB + lane];
        wr[k] = Wr[k * EMB + lane];
    }
    float blv = bl[lane], brv = br[lane];
    int ntiles = (N + GTILE - 1) / GTILE;
    size_t total = (size_t)N * EMB;
    if (blockIdx.x < ntiles) {
        size_t idx = (size_t)blockIdx.x * (GTILE * EMB) + threadIdx.x * 4;
        float4 v = {0.f, 0.f, 0.f, 0.f};
        if (idx + 3 < total) v = *(const float4*)(h + idx);
        else for (int j = 0; j < 4; ++j) ((float*)&v)[j] = (idx + j < total) ? h[idx + j] : 0.f;
        ((float4*)&hs[0][0][0])[threadIdx.x] = v;
    }
    int buf = 0;
    for (int g = blockIdx.x; g < ntiles; g += gridDim.x) {
        __syncthreads();
        int gn = g + gridDim.x;
        if (gn < ntiles) {
            size_t idx = (size_t)gn * (GTILE * EMB) + threadIdx.x * 4;
            float4 v = {0.f, 0.f, 0.f, 0.f};
            if (idx + 3 < total) v = *(const float4*)(h + idx);
            else for (int j = 0; j < 4; ++j) ((float*)&v)[j] = (idx + j < total) ? h[idx + j] : 0.f;
            ((float4*)&hs[buf ^ 1][0][0])[threadIdx.x] = v;
        }
#pragma unroll
        for (int j = 0; j < 4; ++j) {
            int node = g * GTILE + wv * 4 + j;
            if (node < N) {
                const float* hp = &hs[buf][wv * 4 + j][0];
                float l0 = blv, l1 = 0.f, r0 = brv, r1 = 0.f;
#pragma unroll
                for (int kk = 0; kk < EMB / 4; ++kk) {
                    float4 hv = *(const float4*)(hp + kk * 4);
                    l0 = fmaf(hv.x, wl[kk * 4 + 0], l0);
                    r0 = fmaf(hv.x, wr[kk * 4 + 0], r0);
                    l1 = fmaf(hv.y, wl[kk * 4 + 1], l1);
                    r1 = fmaf(hv.y, wr[kk * 4 + 1], r1);
                    l0 = fmaf(hv.z, wl[kk * 4 + 2], l0);
                    r0 = fmaf(hv.z, wr[kk * 4 + 2], r0);
                    l1 = fmaf(hv.w, wl[kk * 4 + 3], l1);
                    r1 = fmaf(hv.w, wr[kk * 4 + 3], r1);
                }
                outL[(size_t)node * EMB + lane] = l0 + l1;
                outR[(size_t)node * EMB + lane] = r0 + r1;
            }
        }
        buf ^= 1;
    }
}

// ---------------- CSR build via 2-level radix partition ----------------
__global__ void bincount_kernel(const int* __restrict__ ei, int* __restrict__ bcount,
                                int* __restrict__ offs, int E, int NB, int N) {
    __shared__ int lh[MAXNB];
    for (int j = threadIdx.x; j < NB; j += 256) lh[j] = 0;
    __syncthreads();
    for (int i = blockIdx.x * 256 + threadIdx.x; i < E; i += gridDim.x * 256)
        atomicAdd(&lh[ei[E + i] >> BSH], 1);
    __syncthreads();
    for (int j = threadIdx.x; j < NB; j += 256)
        if (lh[j]) atomicAdd(&bcount[j], lh[j]);
    if (blockIdx.x == 0 && threadIdx.x == 0) offs[N] = E + N;   // slots incl. selfs
}

__global__ void bscan_kernel(const int* __restrict__ bcount, int* __restrict__ boffs,
                             int* __restrict__ bcursor, int NB) {
    __shared__ int s[1024];
    int t = threadIdx.x;
    int v0 = (t < NB) ? bcount[t] : 0;
    s[t] = v0;
    __syncthreads();
    for (int off = 1; off < 1024; off <<= 1) {
        int v = (t >= off) ? s[t - off] : 0;
        __syncthreads();
        s[t] += v;
        __syncthreads();
    }
    if (t < NB) {
        boffs[t + 1] = s[t];
        bcursor[t] = s[t] - v0;
    }
    if (t == 0) boffs[0] = 0;
}

__global__ void partition_kernel(const int* __restrict__ ei, int* __restrict__ bcursor,
                                 int* __restrict__ epart, int E, int NB) {
    __shared__ int lh[MAXNB];
    for (int j = threadIdx.x; j < NB; j += 256) lh[j] = 0;
    __syncthreads();
    int base = blockIdx.x * PCHUNK;
    int end = min(E, base + PCHUNK);
    for (int i = base + threadIdx.x; i < end; i += 256)
        atomicAdd(&lh[ei[E + i] >> BSH], 1);
    __syncthreads();
    for (int j = threadIdx.x; j < NB; j += 256) {
        int c = lh[j];
        lh[j] = c ? atomicAdd(&bcursor[j], c) : 0;
    }
    __syncthreads();
    for (int i = base + threadIdx.x; i < end; i += 256) {
        int dst = ei[E + i];
        int src = ei[i];
        int slot = atomicAdd(&lh[dst >> BSH], 1);
        epart[slot] = (src << BSH) | (dst & (BSZ - 1));
    }
}

// finalize: per-wave sub-histograms; node n gets deg+1 slots, slot 0 = self.
__global__ void finalize_kernel(const int* __restrict__ epart, const int* __restrict__ boffs,
                                int* __restrict__ offs, int* __restrict__ ssrc, int N) {
    __shared__ int deg4[4][BSZ];
    __shared__ int pos[BSZ];
    __shared__ int cur4[4][BSZ];
    int b = blockIdx.x;
    int t = threadIdx.x;
    int w = t >> 6;
    int n0 = b << BSH;
    int r0 = boffs[b], r1 = boffs[b + 1];
    ((int*)deg4)[t] = 0;
    ((int*)deg4)[t + 256] = 0;
    __syncthreads();
    for (int e = r0 + t; e < r1; e += 256)
        atomicAdd(&deg4[w][epart[e] & (BSZ - 1)], 1);
    __syncthreads();
    int d0 = 0, d1 = 0, d2 = 0, sum = 0;
    if (t < BSZ) {
        d0 = deg4[0][t]; d1 = deg4[1][t]; d2 = deg4[2][t];
        sum = d0 + d1 + d2 + deg4[3][t];
        pos[t] = sum;
    }
    __syncthreads();
    for (int off = 1; off < BSZ; off <<= 1) {
        int v = (t < BSZ && t >= off) ? pos[t - off] : 0;
        __syncthreads();
        if (t < BSZ) pos[t] += v;
        __syncthreads();
    }
    if (t < BSZ) {
        int node = n0 + t;
        int base = r0 + n0 + (pos[t] - sum) + t;   // edges + self-slots before node
        if (node < N) {
            offs[node] = base;
            ssrc[base] = node;                     // self-loop at slot 0
        }
        cur4[0][t] = base + 1;
        cur4[1][t] = base + 1 + d0;
        cur4[2][t] = base + 1 + d0 + d1;
        cur4[3][t] = base + 1 + d0 + d1 + d2;
    }
    __syncthreads();
    for (int e = r0 + t; e < r1; e += 256) {
        int v = epart[e];
        int s = atomicAdd(&cur4[w][v & (BSZ - 1)], 1);
        ssrc[s] = v >> BSH;
    }
}

// ---------------- DPP cross-lane add (VALU pipe; compiler handles hazards) --
template <int CTRL>
__device__ __forceinline__ float dpp_add(float v) {
    union { float f; int i; } u, r;
    u.f = v;
    r.i = __builtin_amdgcn_update_dpp(0, u.i, CTRL, 0xF, 0xF, true);
    return v + r.f;
}

// ---------------- GATv2 layer: 8 edges per wave iteration, pipelined --------
template <int L>
__global__ void gat_kernel(const float* __restrict__ xl, const float* __restrict__ xr,
                           const int* __restrict__ offs, const int* __restrict__ ssrc,
                           const float* __restrict__ att, const float* __restrict__ bias,
                           const float* __restrict__ linW, const float* __restrict__ linb,
                           float* __restrict__ out, int N) {
    int wid = blockIdx.x * 4 + (threadIdx.x >> 6);
    int lane = threadIdx.x & 63;
    if (wid >= N) return;
    int grp = lane >> 4;          // edge slot within the 4-wide half-batch
    int li = lane & 15;           // float4 channel slot
    unsigned cb = (unsigned)li << 2;

    const float LOG2E = 1.4426950408889634f;
    float4 att4 = *(const float4*)(att + cb);
    att4.x *= LOG2E; att4.y *= LOG2E; att4.z *= LOG2E; att4.w *= LOG2E;
    float4 bias4 = *(const float4*)(bias + cb);
    unsigned rb = (unsigned)wid << 6;
    float4 xr4 = *(const float4*)(xr + rb + cb);

    int e0 = offs[wid], e1 = offs[wid + 1];

    float s = 0.f;
    float4 acc = {0.f, 0.f, 0.f, 0.f};

    // prologue: indices for first batch (ssrc padded -> unconditional loads OK)
    unsigned sA = (unsigned)ssrc[e0 + grp];
    unsigned sB = (unsigned)ssrc[e0 + 4 + grp];
    sA = (e0 + grp < e1) ? sA : (unsigned)wid;
    sB = (e0 + 4 + grp < e1) ? sB : (unsigned)wid;

    for (int t = e0; t < e1; t += 8) {
        float4 a = *(const float4*)(xl + (sA << 6) + cb);
        float4 b = *(const float4*)(xl + (sB << 6) + cb);
        int tn = t + 8;
        unsigned nA = (unsigned)ssrc[tn + grp];
        unsigned nB = (unsigned)ssrc[tn + 4 + grp];
        nA = (tn + grp < e1) ? nA : (unsigned)wid;
        nB = (tn + 4 + grp < e1) ? nB : (unsigned)wid;
        bool vA = t + grp < e1;
        bool vB = t + 4 + grp < e1;

        float ux = a.x + xr4.x; ux = fmaxf(ux, 0.2f * ux);
        float uy = a.y + xr4.y; uy = fmaxf(uy, 0.2f * uy);
        float uz = a.z + xr4.z; uz = fmaxf(uz, 0.2f * uz);
        float uw = a.w + xr4.w; uw = fmaxf(uw, 0.2f * uw);
        float pa = att4.x * ux + att4.y * uy + att4.z * uz + att4.w * uw;
        pa = dpp_add<0xB1>(pa);
        pa = dpp_add<0x4E>(pa);
        if (L == 2) {
            pa = dpp_add<0x141>(pa);
            pa = dpp_add<0x140>(pa);
        }
        float pA = exp2f(pa);
        pA = vA ? pA : 0.f;
        s += pA;
        acc.x += pA * a.x; acc.y += pA * a.y; acc.z += pA * a.z; acc.w += pA * a.w;

        float vx = b.x + xr4.x; vx = fmaxf(vx, 0.2f * vx);
        float vy = b.y + xr4.y; vy = fmaxf(vy, 0.2f * vy);
        float vz = b.z + xr4.z; vz = fmaxf(vz, 0.2f * vz);
        float vw = b.w + xr4.w; vw = fmaxf(vw, 0.2f * vw);
        float pb = att4.x * vx + att4.y * vy + att4.z * vz + att4.w * vw;
        pb = dpp_add<0xB1>(pb);
        pb = dpp_add<0x4E>(pb);
        if (L == 2) {
            pb = dpp_add<0x141>(pb);
            pb = dpp_add<0x140>(pb);
        }
        float pB = exp2f(pb);
        pB = vB ? pB : 0.f;
        s += pB;
        acc.x += pB * b.x; acc.y += pB * b.y; acc.z += pB * b.z; acc.w += pB * b.w;

        sA = nA; sB = nB;
    }

    // combine the 4 edge groups (once per node)
    s += __shfl_xor(s, 16); s += __shfl_xor(s, 32);
    acc.x += __shfl_xor(acc.x, 16); acc.x += __shfl_xor(acc.x, 32);
    acc.y += __shfl_xor(acc.y, 16); acc.y += __shfl_xor(acc.y, 32);
    acc.z += __shfl_xor(acc.z, 16); acc.z += __shfl_xor(acc.z, 32);
    acc.w += __shfl_xor(acc.w, 16); acc.w += __shfl_xor(acc.w, 32);

    float inv = 1.f / (s + 1e-16f);
    if (L == 1) {
        float4 val;
        val.x = acc.x * inv + bias4.x;
        val.y = acc.y * inv + bias4.y;
        val.z = acc.z * inv + bias4.z;
        val.w = acc.w * inv + bias4.w;
        val.x = (val.x > 0.f) ? val.x : (__expf(val.x) - 1.f);
        val.y = (val.y > 0.f) ? val.y : (__expf(val.y) - 1.f);
        val.z = (val.z > 0.f) ? val.z : (__expf(val.z) - 1.f);
        val.w = (val.w > 0.f) ? val.w : (__expf(val.w) - 1.f);
        if (grp == 0) *(float4*)(out + rb + cb) = val;
    } else {
        float4 lw = *(const float4*)(linW + cb);
        float r = (acc.x * inv + bias4.x) * lw.x + (acc.y * inv + bias4.y) * lw.y +
                  (acc.z * inv + bias4.z) * lw.z + (acc.w * inv + bias4.w) * lw.w;
        r = dpp_add<0xB1>(r);
        r = dpp_add<0x4E>(r);
        r = dpp_add<0x141>(r);
        r = dpp_add<0x140>(r);
        if (lane == 0) out[wid] = r + linb[0];
    }
}

extern "C" void kernel_launch(void* const* d_in, const int* in_sizes, int n_in,
                              void* d_out, int out_size, void* d_ws, size_t ws_size,
                              hipStream_t stream) {
    const int* x = (const int*)d_in[0];
    const int* ei = (const int*)d_in[1];          // int32 marshalled
    const float* birth_tab = (const float*)d_in[2];
    const float* gender_tab = (const float*)d_in[3];
    const float* symp_tab = (const float*)d_in[4];
    const float* Wl1 = (const float*)d_in[5];
    const float* bl1 = (const float*)d_in[6];
    const float* Wr1 = (const float*)d_in[7];
    const float* br1 = (const float*)d_in[8];
    const float* att1 = (const float*)d_in[9];
    const float* bias1 = (const float*)d_in[10];
    const float* Wl2 = (const float*)d_in[11];
    const float* bl2 = (const float*)d_in[12];
    const float* Wr2 = (const float*)d_in[13];
    const float* br2 = (const float*)d_in[14];
    const float* att2 = (const float*)d_in[15];
    const float* bias2 = (const float*)d_in[16];
    const float* linW = (const float*)d_in[17];
    const float* linb = (const float*)d_in[18];
    float* outp = (float*)d_out;

    int N = in_sizes[0] / XCOLS;   // 100000
    int E = in_sizes[1] / 2;       // 1600000
    int NB = (N + BSZ - 1) >> BSH; // 782

    char* p = (char*)d_ws;
    auto alloc = [&](size_t bytes) {
        void* r = (void*)p;
        p += (bytes + 255) & ~(size_t)255;
        return r;
    };
    float* h0 = (float*)alloc((size_t)N * EMB * 4);
    float* bufA = (float*)alloc((size_t)N * EMB * 4);
    float* bufB = (float*)alloc((size_t)N * EMB * 4);
    int* bcount = (int*)alloc(MAXNB * 4);
    int* boffs = (int*)alloc((MAXNB + 1) * 4);
    int* bcursor = (int*)alloc(MAXNB * 4);
    int* offs = (int*)alloc((size_t)(N + 1) * 4);
    int* epart = (int*)alloc((size_t)E * 4);
    int* ssrc = (int*)alloc((size_t)(E + N + 64) * 4);  // edges + selfs + pad
    float* tL = (float*)alloc((size_t)TROWS * EMB * 4);
    float* tR = (float*)alloc((size_t)TROWS * EMB * 4);

    int ngrp = (N + 3) / 4;

    // CSR build (2-level radix partition; self-loops added in finalize)
    zero_kernel<<<(NB + 255) / 256, 256, 0, stream>>>(bcount, NB);
    bincount_kernel<<<512, 256, 0, stream>>>(ei, bcount, offs, E, NB, N);
    bscan_kernel<<<1, 1024, 0, stream>>>(bcount, boffs, bcursor, NB);
    partition_kernel<<<(E + PCHUNK - 1) / PCHUNK, 256, 0, stream>>>(ei, bcursor, epart, E, NB);
    finalize_kernel<<<NB, 256, 0, stream>>>(epart, boffs, offs, ssrc, N);

    // node pipeline: tables -> (embed+GEMM1 fused via linearity) -> gat1 -> GEMM2 -> gat2
    transform_kernel<<<TROWS, 64, 0, stream>>>(birth_tab, gender_tab, symp_tab,
                                               Wl1, Wr1, tL, tR);
    embedgemm_kernel<<<ngrp, 256, 0, stream>>>(x, tL, tR, bl1, br1, bufA, bufB, N);
    gat_kernel<1><<<ngrp, 256, 0, stream>>>(bufA, bufB, offs, ssrc, att1, bias1,
                                            nullptr, nullptr, h0, N);
    gemm_dual_kernel<<<768, 256, 0, stream>>>(h0, Wl2, bl2, Wr2, br2, bufA, bufB, N);
    gat_kernel<2><<<ngrp, 256, 0, stream>>>(bufA, bufB, offs, ssrc, att2, bias2,
                                            linW, linb, outp, N);
}